// Round 8
// baseline (276.717 us; speedup 1.0000x reference)
//
#include <hip/hip_runtime.h>

#define N_NODES   100000
#define D_DIM     16
#define NFILT     8
#define KOUT      128
#define NNZ_CNT   1600000

// two-level binning geometry
#define SHIFT1    12
#define NC1       25                                   // coarse buckets (key>>12)
#define CAP1      67072                                // slots per coarse (mu 64000 + ~12 sigma)
#define NSUB      64                                   // sub-buckets per coarse
#define CROWS     64                                   // keys per final bucket
#define NCB       (NC1 * NSUB)                         // 1600 final buckets
#define CAP       1280                                 // final bucket slots (mu 1024 + 8 sigma)
#define EPB       2048                                 // edges/records per bin block
#define NBLKA     ((NNZ_CNT + EPB - 1) / EPB)          // 782 coarse blocks
#define CHB       ((CAP1 + EPB - 1) / EPB)             // 33 chunks per coarse in binF
#define NBF       (NC1 * CHB)                          // 825 binF blocks
#define CPAD      16                                   // ints per cursor = one 64B line

// shared-memory overlay (ints): binF needs 256 + 2*EPB + EPB/4 = 4864 (19.5 KB);
// sg1 needs 256 + 2*CAP = 2816. One 4864-int buffer serves both paths.
#define SMEM_INTS 4864

// combo[node] = 64B line: [0..7]=LTx bf16 pairs (u32), [8..11]=wav bf16 (u16 x8).

// fp32 -> bf16 bits with round-to-nearest-even (same as __float2bfloat16)
__device__ __forceinline__ uint f32_to_bf16_bits(float f) {
    uint u = __float_as_uint(f);
    uint r = (u + 0x7FFFu + ((u >> 16) & 1u)) >> 16;
    return r;
}

// binC2: FUSED coarse binning for both orderings + folded wav filter bank.
// Stages 2048 edges in registers ONCE, then runs two phases (key=col ->
// regBc, key=row -> regBr) reusing the same LDS machinery. Runs ~82 rec =
// 656B -> coalesced copy-out (round-5 lesson: scattered 8B stores cost
// ~100 MB of line RMW). Each block also computes wav for 128 nodes.
// Record: x = ((key & 4095) << 17) | payload   (12 key bits survive to binF).
__global__ __launch_bounds__(512) void binC2_kernel(const int* __restrict__ rows,
                                                    const int* __restrict__ cols,
                                                    const float* __restrict__ v,
                                                    const float* __restrict__ eig,
                                                    int* __restrict__ gc1c,
                                                    int* __restrict__ gc1r,
                                                    int2* __restrict__ regBc,
                                                    int2* __restrict__ regBr,
                                                    uint* __restrict__ combo) {
    __shared__ int cnt[NC1], offb[NC1], gbase[NC1], cur[NC1];
    __shared__ int2 rec[EPB];
    __shared__ unsigned char rbk[EPB];
    int tid = threadIdx.x;
    int e0 = blockIdx.x * EPB;
    int nE = NNZ_CNT - e0; if (nE > EPB) nE = EPB;

    // folded wav: 128 nodes per block, w_wav[n,f] = t^(2^f) - t^(2^(f+1))
    {
        int n = blockIdx.x * 128 + tid;
        if (tid < 128 && n < N_NODES) {
            float curw = expf(-eig[n]);
            uint pk[4];
#pragma unroll
            for (int h = 0; h < 4; ++h) {
                float nx0 = curw * curw;
                float w0 = curw - nx0;
                float nx1 = nx0 * nx0;
                float w1 = nx0 - nx1;
                curw = nx1;
                pk[h] = f32_to_bf16_bits(w0) | (f32_to_bf16_bits(w1) << 16);
            }
            *(uint4*)(combo + (size_t)n * 16 + 8) = make_uint4(pk[0], pk[1], pk[2], pk[3]);
        }
    }

    int r_[4], c_[4], vb_[4];
    int nk = 0;
#pragma unroll
    for (int kk = 0; kk < 4; ++kk) {
        int i = tid + kk * 512;
        if (i < nE) {
            r_[kk] = rows[e0 + i];
            c_[kk] = cols[e0 + i];
            vb_[kk] = __float_as_int(v[e0 + i]);
            nk = kk + 1;
        }
    }

    // ---- phase A: key = col, payload = row -> regBc ----
    if (tid < NC1) cnt[tid] = 0;
    __syncthreads();
    for (int kk = 0; kk < nk; ++kk) atomicAdd(&cnt[c_[kk] >> SHIFT1], 1);
    __syncthreads();
    if (tid == 0) { int run = 0; for (int b = 0; b < NC1; ++b) { offb[b] = run; run += cnt[b]; } }
    __syncthreads();
    if (tid < NC1) {
        gbase[tid] = cnt[tid] ? atomicAdd(&gc1c[tid * CPAD], cnt[tid]) : 0;
        cur[tid] = offb[tid];
    }
    __syncthreads();
    for (int kk = 0; kk < nk; ++kk) {
        int b = c_[kk] >> SHIFT1;
        int pos = atomicAdd(&cur[b], 1);
        rec[pos] = make_int2(((c_[kk] & 4095) << 17) | r_[kk], vb_[kk]);
        rbk[pos] = (unsigned char)b;
    }
    __syncthreads();
    for (int i = tid; i < nE; i += 512) {
        int b = rbk[i];
        int slot = gbase[b] + (i - offb[b]);
        if (slot < CAP1) regBc[(size_t)b * CAP1 + slot] = rec[i];
    }
    __syncthreads();

    // ---- phase B: key = row, payload = col -> regBr ----
    if (tid < NC1) cnt[tid] = 0;
    __syncthreads();
    for (int kk = 0; kk < nk; ++kk) atomicAdd(&cnt[r_[kk] >> SHIFT1], 1);
    __syncthreads();
    if (tid == 0) { int run = 0; for (int b = 0; b < NC1; ++b) { offb[b] = run; run += cnt[b]; } }
    __syncthreads();
    if (tid < NC1) {
        gbase[tid] = cnt[tid] ? atomicAdd(&gc1r[tid * CPAD], cnt[tid]) : 0;
        cur[tid] = offb[tid];
    }
    __syncthreads();
    for (int kk = 0; kk < nk; ++kk) {
        int b = r_[kk] >> SHIFT1;
        int pos = atomicAdd(&cur[b], 1);
        rec[pos] = make_int2(((r_[kk] & 4095) << 17) | c_[kk], vb_[kk]);
        rbk[pos] = (unsigned char)b;
    }
    __syncthreads();
    for (int i = tid; i < nE; i += 512) {
        int b = rbk[i];
        int slot = gbase[b] + (i - offb[b]);
        if (slot < CAP1) regBr[(size_t)b * CAP1 + slot] = rec[i];
    }
}

// binF body: fine binning. Block = one 2048-record chunk of one coarse
// bucket; bins into 64 sub-buckets (runs ~32 rec = 256B, coalesced).
// sub = record bits 23..28. Output keeps 6 low key bits:
// x = (keylow6 << 17) | payload  (mask 0x7FFFFF).
__device__ __forceinline__ void binF_body(int bfb,
                                          const int* __restrict__ gcur1,
                                          const int2* __restrict__ regB,
                                          int* __restrict__ gcurF,
                                          int2* __restrict__ regA,
                                          int* sm) {
    int* cnt   = sm;
    int* offb  = sm + NSUB;
    int* gbase = sm + 2 * NSUB;
    int* cur   = sm + 3 * NSUB;
    int2* rec  = (int2*)(sm + 256);
    unsigned char* rbk = (unsigned char*)(sm + 256 + 2 * EPB);
    int tid = threadIdx.x;
    int cb = bfb / CHB;
    int ch = bfb % CHB;
    int nc = gcur1[cb * CPAD]; if (nc > CAP1) nc = CAP1;
    int cs = ch * EPB;
    if (cs >= nc) return;                 // uniform early-exit
    int nE = nc - cs; if (nE > EPB) nE = EPB;
    size_t srcb = (size_t)cb * CAP1 + cs;

    if (tid < NSUB) cnt[tid] = 0;
    __syncthreads();

    int2 my[4]; int msub[4];
    int nk = 0;
#pragma unroll
    for (int kk = 0; kk < 4; ++kk) {
        int i = tid + kk * 512;
        msub[kk] = -1;
        if (i < nE) {
            my[kk] = regB[srcb + i];
            msub[kk] = (my[kk].x >> 23) & (NSUB - 1);
            nk = kk + 1;
            atomicAdd(&cnt[msub[kk]], 1);
        }
    }
    __syncthreads();

    if (tid == 0) { int run = 0; for (int b = 0; b < NSUB; ++b) { offb[b] = run; run += cnt[b]; } }
    __syncthreads();
    if (tid < NSUB) {
        gbase[tid] = cnt[tid] ? atomicAdd(&gcurF[(cb * NSUB + tid) * CPAD], cnt[tid]) : 0;
        cur[tid] = offb[tid];
    }
    __syncthreads();

    for (int kk = 0; kk < nk; ++kk)
        if (msub[kk] >= 0) {
            int pos = atomicAdd(&cur[msub[kk]], 1);
            rec[pos] = make_int2(my[kk].x & 0x7FFFFF, my[kk].y);  // keylow(6) | payload(17)
            rbk[pos] = (unsigned char)msub[kk];
        }
    __syncthreads();

    for (int i = tid; i < nE; i += 512) {
        int b = rbk[i];
        int slot = gbase[b] + (i - offb[b]);
        if (slot < CAP)
            regA[(size_t)(cb * NSUB + b) * CAP + slot] = rec[i];
    }
}

__global__ __launch_bounds__(512) void binF_kernel(const int* __restrict__ gcur1,
                                                   const int2* __restrict__ regB,
                                                   int* __restrict__ gcurF,
                                                   int2* __restrict__ regA) {
    __shared__ alignas(16) int sm[SMEM_INTS];
    binF_body(blockIdx.x, gcur1, regB, gcurF, regA, sm);
}

// sg1 body: fused sort+gather for pass 1 (one block per COLUMN bucket,
// 64 cols, 512 thr). Records -> registers + LDS histogram, scan 64, scatter
// into col-sorted LDS rec[]; then per column, 16-lane x 4-subgroup walk
// (rec via free LDS broadcast, x row = coalesced 64B), shfl reduce, pack
// bf16 pairs {d,d+8} into combo[c][0..7].
__device__ __forceinline__ void sg1_body(int b,
                                         const int* __restrict__ gcurF,
                                         const int2* __restrict__ regA,
                                         const float* __restrict__ x,
                                         uint* __restrict__ combo,
                                         int* sm) {
    int* cnt = sm;
    int* sc  = sm + CROWS;
    int* st  = sm + 2 * CROWS;
    int* cur = sm + 3 * CROWS;
    int2* rec = (int2*)(sm + 256);
    int tid = threadIdx.x;
    int nb = gcurF[b * CPAD]; if (nb > CAP) nb = CAP;
    size_t base = (size_t)b * CAP;

    int2 my[3]; int mkey[3];
    if (tid < CROWS) cnt[tid] = 0;
    __syncthreads();
#pragma unroll
    for (int s = 0; s < 3; ++s) {
        int i = tid + s * 512;
        mkey[s] = -1;
        if (i < nb) {
            my[s] = regA[base + i];
            mkey[s] = my[s].x >> 17;
            atomicAdd(&cnt[mkey[s]], 1);
        }
    }
    __syncthreads();

    int cv = (tid < CROWS) ? cnt[tid] : 0;
    if (tid < CROWS) sc[tid] = cv;
    __syncthreads();
    for (int off = 1; off < CROWS; off <<= 1) {
        int t = (tid < CROWS && tid >= off) ? sc[tid - off] : 0;
        __syncthreads();
        if (tid < CROWS) sc[tid] += t;
        __syncthreads();
    }
    if (tid < CROWS) { int s0 = sc[tid] - cv; st[tid] = s0; cur[tid] = s0; }
    __syncthreads();

#pragma unroll
    for (int s = 0; s < 3; ++s)
        if (mkey[s] >= 0) {
            int pos = atomicAdd(&cur[mkey[s]], 1);
            if (pos < CAP) rec[pos] = make_int2(my[s].x & 0x1FFFF, my[s].y);
        }
    __syncthreads();

    // gather: 8 waves x 8 cols; lane = (j<<4)|d, 4 records in flight per col
    int wave = tid >> 6, lane = tid & 63;
    int d = lane & 15, j = lane >> 4;
    for (int cl = wave; cl < CROWS; cl += 8) {
        int c = b * CROWS + cl;
        int i0 = st[cl], e0 = i0 + cnt[cl]; if (e0 > CAP) e0 = CAP;
        float acc = 0.f;
        for (int i = i0 + j; i < e0; i += 4) {
            int2 e = rec[i];                         // 16-lane LDS broadcast
            acc = fmaf(__int_as_float(e.y), x[(size_t)e.x * D_DIM + d], acc);
        }
        acc += __shfl_xor(acc, 16);
        acc += __shfl_xor(acc, 32);
        float hi = __shfl_down(acc, 8);
        if (lane < 8 && c < N_NODES)
            combo[(size_t)c * 16 + lane] =
                f32_to_bf16_bits(acc) | (f32_to_bf16_bits(hi) << 16);
    }
}

// Merged dispatch: binF-row (blocks [0,NBF)) and sortgather1 (blocks
// [NBF,NBF+NCB)) are mutually independent (binF-row needs binC2; sg1 needs
// binF-col) and have complementary profiles (BW-streaming vs latency-bound
// gather) -> co-schedule them in one kernel to overlap.
__global__ __launch_bounds__(512) void binFr_sg1_kernel(const int* __restrict__ gc1r,
                                                        const int2* __restrict__ regBr,
                                                        int* __restrict__ gfr,
                                                        int2* __restrict__ regAr,
                                                        const int* __restrict__ gfc,
                                                        const int2* __restrict__ regAc,
                                                        const float* __restrict__ x,
                                                        uint* __restrict__ combo) {
    __shared__ alignas(16) int sm[SMEM_INTS];
    int bb = blockIdx.x;
    if (bb < NBF) binF_body(bb, gc1r, regBr, gfr, regAr, sm);
    else          sg1_body(bb - NBF, gfc, regAc, x, combo, sm);
}

// Fused sort+gather for pass 2 (one block per ROW bucket, 64 rows, 256 thr).
// Reg-staged LDS sort; gather reads ONE combo line per record (LTx pairs +
// wav in the same 64B). out stores nontemporal: 51 MB of write-once lines
// must not evict the combo working set.
__global__ __launch_bounds__(256) void sortgather2_kernel(const int* __restrict__ gcurF,
                                                          const int2* __restrict__ regA,
                                                          const uint* __restrict__ combo,
                                                          float* __restrict__ out) {
    __shared__ int2 rec[CAP];        // 10 KB, row-sorted: (col, vbits)
    __shared__ int cnt[CROWS], sc[CROWS], st[CROWS], cur[CROWS];
    int tid = threadIdx.x;
    int b = blockIdx.x;
    int nb = gcurF[b * CPAD]; if (nb > CAP) nb = CAP;
    size_t base = (size_t)b * CAP;

    int2 my[5]; int mkey[5];
    if (tid < CROWS) cnt[tid] = 0;
    __syncthreads();
#pragma unroll
    for (int s = 0; s < 5; ++s) {
        int i = tid + s * 256;
        mkey[s] = -1;
        if (i < nb) {
            my[s] = regA[base + i];
            mkey[s] = my[s].x >> 17;
            atomicAdd(&cnt[mkey[s]], 1);
        }
    }
    __syncthreads();

    int cv = (tid < CROWS) ? cnt[tid] : 0;
    if (tid < CROWS) sc[tid] = cv;
    __syncthreads();
    for (int off = 1; off < CROWS; off <<= 1) {
        int t = (tid < CROWS && tid >= off) ? sc[tid - off] : 0;
        __syncthreads();
        if (tid < CROWS) sc[tid] += t;
        __syncthreads();
    }
    if (tid < CROWS) { int s0 = sc[tid] - cv; st[tid] = s0; cur[tid] = s0; }
    __syncthreads();

#pragma unroll
    for (int s = 0; s < 5; ++s)
        if (mkey[s] >= 0) {
            int pos = atomicAdd(&cur[mkey[s]], 1);
            if (pos < CAP) rec[pos] = make_int2(my[s].x & 0x1FFFF, my[s].y);
        }
    __syncthreads();

    // gather: 4 waves x 16 rows; lane owns outputs (lane) and (lane+64)
    int wave = tid >> 6, lane = tid & 63;
    int d0 = lane >> 3;        // pair index 0..7
    int f  = lane & 7;         // 0..7
    for (int rl = wave; rl < CROWS; rl += 4) {
        int row = b * CROWS + rl;
        if (row >= N_NODES) continue;
        int i = st[rl], end = st[rl] + cnt[rl]; if (end > CAP) end = CAP;
        float acc0 = 0.f, acc1 = 0.f;
        for (; i + 4 <= end; i += 4) {
            int2 e0 = rec[i], e1 = rec[i + 1], e2 = rec[i + 2], e3 = rec[i + 3];
            uint l0 = combo[(size_t)e0.x * 16 + d0];
            uint l1 = combo[(size_t)e1.x * 16 + d0];
            uint l2 = combo[(size_t)e2.x * 16 + d0];
            uint l3 = combo[(size_t)e3.x * 16 + d0];
            uint w0 = ((const ushort*)(combo + (size_t)e0.x * 16 + 8))[f];
            uint w1 = ((const ushort*)(combo + (size_t)e1.x * 16 + 8))[f];
            uint w2 = ((const ushort*)(combo + (size_t)e2.x * 16 + 8))[f];
            uint w3 = ((const ushort*)(combo + (size_t)e3.x * 16 + 8))[f];
            float vw0 = __int_as_float(e0.y) * __uint_as_float(w0 << 16);
            float vw1 = __int_as_float(e1.y) * __uint_as_float(w1 << 16);
            float vw2 = __int_as_float(e2.y) * __uint_as_float(w2 << 16);
            float vw3 = __int_as_float(e3.y) * __uint_as_float(w3 << 16);
            acc0 = fmaf(vw0, __uint_as_float(l0 << 16), acc0);
            acc1 = fmaf(vw0, __uint_as_float(l0 & 0xFFFF0000u), acc1);
            acc0 = fmaf(vw1, __uint_as_float(l1 << 16), acc0);
            acc1 = fmaf(vw1, __uint_as_float(l1 & 0xFFFF0000u), acc1);
            acc0 = fmaf(vw2, __uint_as_float(l2 << 16), acc0);
            acc1 = fmaf(vw2, __uint_as_float(l2 & 0xFFFF0000u), acc1);
            acc0 = fmaf(vw3, __uint_as_float(l3 << 16), acc0);
            acc1 = fmaf(vw3, __uint_as_float(l3 & 0xFFFF0000u), acc1);
        }
        for (; i < end; ++i) {
            int2 e = rec[i];
            uint l = combo[(size_t)e.x * 16 + d0];
            uint w = ((const ushort*)(combo + (size_t)e.x * 16 + 8))[f];
            float vw = __int_as_float(e.y) * __uint_as_float(w << 16);
            acc0 = fmaf(vw, __uint_as_float(l << 16), acc0);
            acc1 = fmaf(vw, __uint_as_float(l & 0xFFFF0000u), acc1);
        }
        __builtin_nontemporal_store(acc0, &out[(size_t)row * KOUT + lane]);
        __builtin_nontemporal_store(acc1, &out[(size_t)row * KOUT + 64 + lane]);
    }
}

extern "C" void kernel_launch(void* const* d_in, const int* in_sizes, int n_in,
                              void* d_out, int out_size, void* d_ws, size_t ws_size,
                              hipStream_t stream) {
    const float* x      = (const float*)d_in[0];
    const int*   L_rows = (const int*)  d_in[1];
    const int*   L_cols = (const int*)  d_in[2];
    const float* L_v    = (const float*)d_in[3];
    const float* eig    = (const float*)d_in[4];
    float* out = (float*)d_out;

    // workspace layout (~66.3 MB): combo 6.4 + regBc/regBr 13.4 each +
    // regAc/regAr 16.4 each + cursors 0.2. Two regA buffers because
    // binF-row and sortgather1 run CONCURRENTLY in the merged dispatch.
    uint* combo = (uint*)d_ws;                                // [N*16]       6.4 MB (64B/node)
    int2* regBc = (int2*)(combo + (size_t)N_NODES * 16);      // [NC1*CAP1]  13.4 MB
    int2* regBr = regBc + (size_t)NC1 * CAP1;                 // [NC1*CAP1]  13.4 MB
    int2* regAc = regBr + (size_t)NC1 * CAP1;                 // [NCB*CAP]   16.4 MB
    int2* regAr = regAc + (size_t)NCB * CAP;                  // [NCB*CAP]   16.4 MB
    int*  gc1c  = (int*)(regAr + (size_t)NCB * CAP);          // coarse cursors (col)
    int*  gc1r  = gc1c + NC1 * CPAD;                          // coarse cursors (row)
    int*  gfc   = gc1r + NC1 * CPAD;                          // final cursors (col)
    int*  gfr   = gfc + NCB * CPAD;                           // final cursors (row)

    hipMemsetAsync(gc1c, 0, (size_t)(2 * NC1 + 2 * NCB) * CPAD * sizeof(int), stream);

    // K1: fused coarse binning (both orderings) + wav filter bank
    binC2_kernel<<<NBLKA, 512, 0, stream>>>(L_rows, L_cols, L_v, eig,
                                            gc1c, gc1r, regBc, regBr, combo);

    // K2: fine bin, COLUMN ordering
    binF_kernel<<<NBF, 512, 0, stream>>>(gc1c, regBc, gfc, regAc);

    // K3: fine bin ROW ordering  ||  fused sort+gather pass 1 (independent)
    binFr_sg1_kernel<<<NBF + NCB, 512, 0, stream>>>(gc1r, regBr, gfr, regAr,
                                                    gfc, regAc, x, combo);

    // K4: fused sort+gather pass 2 -> out
    sortgather2_kernel<<<NCB, 256, 0, stream>>>(gfr, regAr, combo, out);
}